// Round 4
// baseline (50.865 us; speedup 1.0000x reference)
//
#include <hip/hip_runtime.h>

#define NUM_CLASSES 100
#define QUEUE_SIZE  256
#define FEATURE_DIM 1024
#define BATCH       4096
#define TOTAL_ROWS  (NUM_CLASSES * QUEUE_SIZE)   // 25600
#define EPS         1e-12f
#define ROWS_PER_BLOCK 8
#define SLOT_BLOCKS (BATCH / 256)                // 16
#define NORM_BLOCKS (BATCH / 4)                  // 1024 (4 waves/block, 1 row/wave)

typedef float f32x4 __attribute__((ext_vector_type(4)));

// ---------------------------------------------------------------------------
// Kernel 1 (combined prep):
//  blocks [0, 16):    FIFO slot computation -> inv[row] = last batch idx b
//                     (inv pre-initialized to -1 via memsetAsync 0xFF)
//  blocks [16, 1040): per-row L2 norm of embeddings -> scale[b] = 1/max(||e||,eps)
//                     one wave per row, shfl-only reduction
// ---------------------------------------------------------------------------
__global__ __launch_bounds__(256) void prep_kernel(
    const float* __restrict__ emb,
    const int* __restrict__ labels,
    const int* __restrict__ queue_ptr,
    int* __restrict__ inv,
    float* __restrict__ scale)
{
    if (blockIdx.x < SLOT_BLOCKS) {
        __shared__ int hist[NUM_CLASSES];
        __shared__ int s_lab[256];

        const int tid = threadIdx.x;
        const int chunk_start = blockIdx.x * 256;

        for (int i = tid; i < NUM_CLASSES; i += 256) hist[i] = 0;
        __syncthreads();

        // histogram of labels[0 .. chunk_start)
        for (int j = tid; j < chunk_start; j += 256) {
            atomicAdd(&hist[labels[j]], 1);
        }
        s_lab[tid] = labels[chunk_start + tid];
        __syncthreads();

        const int lab = s_lab[tid];
        int rank = hist[lab];
        for (int j = 0; j < tid; ++j) {
            rank += (s_lab[j] == lab) ? 1 : 0;
        }
        const int slot = (queue_ptr[lab] + rank) & (QUEUE_SIZE - 1);
        const int row  = lab * QUEUE_SIZE + slot;
        atomicMax(&inv[row], chunk_start + tid);   // last-write-wins FIFO
    } else {
        const int tid  = threadIdx.x;
        const int wave = tid >> 6;
        const int lane = tid & 63;
        const int b = (blockIdx.x - SLOT_BLOCKS) * 4 + wave;

        const f32x4* src = reinterpret_cast<const f32x4*>(emb + (long)b * FEATURE_DIM);
        float ss = 0.0f;
        #pragma unroll
        for (int it = 0; it < 4; ++it) {
            f32x4 v = src[it * 64 + lane];
            ss += v.x * v.x + v.y * v.y + v.z * v.z + v.w * v.w;
        }
        #pragma unroll
        for (int off = 32; off; off >>= 1) {
            ss += __shfl_xor(ss, off, 64);
        }
        if (lane == 0) {
            scale[b] = 1.0f / fmaxf(sqrtf(ss), EPS);
        }
    }
}

// ---------------------------------------------------------------------------
// Kernel 2: pure streaming writer. 8 rows per 256-thread block.
//  src_i = (inv[row_i] < 0) ? queue row (scale 1.0) : emb row (scale 1/norm)
//  Plain cached loads (L3 serves replays); nontemporal stores (out never
//  re-read in timed region, keeps queue/emb L3-resident).
// ---------------------------------------------------------------------------
__global__ __launch_bounds__(256) void fused_write_kernel(
    const float* __restrict__ queue,
    const float* __restrict__ emb,
    const int* __restrict__ inv,
    const float* __restrict__ scale,
    float* __restrict__ out)
{
    const int tid  = threadIdx.x;
    const int row0 = blockIdx.x * ROWS_PER_BLOCK;

    __shared__ int   s_b[ROWS_PER_BLOCK];
    __shared__ float s_s[ROWS_PER_BLOCK];
    if (tid < ROWS_PER_BLOCK) {
        const int b = inv[row0 + tid];
        s_b[tid] = b;
        s_s[tid] = (b < 0) ? 1.0f : scale[b];
    }
    __syncthreads();

    f32x4 v[ROWS_PER_BLOCK];
    #pragma unroll
    for (int i = 0; i < ROWS_PER_BLOCK; ++i) {
        const int b = s_b[i];
        const f32x4* src = (b < 0)
            ? reinterpret_cast<const f32x4*>(queue + (long)(row0 + i) * FEATURE_DIM)
            : reinterpret_cast<const f32x4*>(emb + (long)b * FEATURE_DIM);
        v[i] = src[tid];
    }

    #pragma unroll
    for (int i = 0; i < ROWS_PER_BLOCK; ++i) {
        f32x4 o = v[i] * s_s[i];
        f32x4* dst = reinterpret_cast<f32x4*>(out + (long)(row0 + i) * FEATURE_DIM);
        __builtin_nontemporal_store(o, &dst[tid]);
    }
}

// ---------------------------------------------------------------------------
extern "C" void kernel_launch(void* const* d_in, const int* in_sizes, int n_in,
                              void* d_out, int out_size, void* d_ws, size_t ws_size,
                              hipStream_t stream)
{
    const float* embeddings = (const float*)d_in[0];   // (4096, 1024) f32
    const int*   labels     = (const int*)d_in[1];     // (4096,) int
    const float* queue      = (const float*)d_in[2];   // (100, 256, 1024) f32
    const int*   queue_ptr  = (const int*)d_in[3];     // (100,) int

    float* out   = (float*)d_out;                      // (100, 256, 1024) f32
    int*   inv   = (int*)d_ws;                         // 25600 ints
    float* scale = (float*)((char*)d_ws + TOTAL_ROWS * sizeof(int)); // 4096 f32

    // 0) inv = -1
    (void)hipMemsetAsync(inv, 0xFF, TOTAL_ROWS * sizeof(int), stream);

    // 1) slots + norms in one dispatch
    prep_kernel<<<SLOT_BLOCKS + NORM_BLOCKS, 256, 0, stream>>>(
        embeddings, labels, queue_ptr, inv, scale);

    // 2) streaming fused writer: 8 rows/block
    fused_write_kernel<<<TOTAL_ROWS / ROWS_PER_BLOCK, 256, 0, stream>>>(
        queue, embeddings, inv, scale, out);
}

// Round 5
// 48.757 us; speedup vs baseline: 1.0432x; 1.0432x over previous
//
#include <hip/hip_runtime.h>

#define NUM_CLASSES 100
#define QUEUE_SIZE  256
#define FEATURE_DIM 1024
#define BATCH       4096
#define TOTAL_ROWS  (NUM_CLASSES * QUEUE_SIZE)   // 25600
#define EPS         1e-12f

typedef float f32x4 __attribute__((ext_vector_type(4)));

// ---------------------------------------------------------------------------
// Kernel 1: FIFO slot computation -> inverse map.
// rank[b] = #{ b' < b : labels[b'] == labels[b] }  (serial FIFO semantics)
// row[b]  = labels[b]*QUEUE_SIZE + (queue_ptr[labels[b]] + rank[b]) % QUEUE_SIZE
// inv[row] = max b mapping to row (atomicMax == serial last-write-wins).
// inv pre-initialized to -1 via memsetAsync(0xFF).
// ---------------------------------------------------------------------------
__global__ __launch_bounds__(256) void compute_slots_kernel(
    const int* __restrict__ labels,
    const int* __restrict__ queue_ptr,
    int* __restrict__ inv)
{
    __shared__ int hist[NUM_CLASSES];
    __shared__ int s_lab[256];

    const int tid = threadIdx.x;
    const int chunk_start = blockIdx.x * 256;

    for (int i = tid; i < NUM_CLASSES; i += 256) hist[i] = 0;
    __syncthreads();

    for (int j = tid; j < chunk_start; j += 256) {
        atomicAdd(&hist[labels[j]], 1);
    }
    s_lab[tid] = labels[chunk_start + tid];
    __syncthreads();

    const int lab = s_lab[tid];
    int rank = hist[lab];
    for (int j = 0; j < tid; ++j) {
        rank += (s_lab[j] == lab) ? 1 : 0;
    }
    const int slot = (queue_ptr[lab] + rank) & (QUEUE_SIZE - 1);
    const int row  = lab * QUEUE_SIZE + slot;
    atomicMax(&inv[row], chunk_start + tid);
}

// ---------------------------------------------------------------------------
// Kernel 2: fused writer, one WAVE per row (4 waves / 256-thread block).
// No LDS, no __syncthreads; wave-uniform branch; shfl-only norm reduction.
//  inv[row] >= 0 -> normalize embedding row inv[row], write it
//  inv[row] <  0 -> copy queue row
// Cached loads (L3-resident queue/emb across replays); nontemporal stores
// (out never re-read -> don't evict the read working set from L3).
// ---------------------------------------------------------------------------
__global__ __launch_bounds__(256) void fused_write_kernel(
    const float* __restrict__ queue,
    const float* __restrict__ emb,
    const int* __restrict__ inv,
    float* __restrict__ out)
{
    const int tid  = threadIdx.x;
    const int lane = tid & 63;
    const int wave = tid >> 6;
    const int row  = blockIdx.x * 4 + wave;
    const long base = (long)row * FEATURE_DIM;

    const int b = inv[row];   // wave-uniform
    f32x4* dst = reinterpret_cast<f32x4*>(out + base);

    if (b < 0) {
        // stream-copy path: 4 independent load->store chains per lane
        const f32x4* src = reinterpret_cast<const f32x4*>(queue + base);
        f32x4 v0 = src[lane];
        f32x4 v1 = src[lane + 64];
        f32x4 v2 = src[lane + 128];
        f32x4 v3 = src[lane + 192];
        __builtin_nontemporal_store(v0, &dst[lane]);
        __builtin_nontemporal_store(v1, &dst[lane + 64]);
        __builtin_nontemporal_store(v2, &dst[lane + 128]);
        __builtin_nontemporal_store(v3, &dst[lane + 192]);
    } else {
        // normalize-and-scatter path (wave-local reduction, no LDS)
        const f32x4* src = reinterpret_cast<const f32x4*>(emb + (long)b * FEATURE_DIM);
        f32x4 v0 = src[lane];
        f32x4 v1 = src[lane + 64];
        f32x4 v2 = src[lane + 128];
        f32x4 v3 = src[lane + 192];

        float ss = v0.x*v0.x + v0.y*v0.y + v0.z*v0.z + v0.w*v0.w
                 + v1.x*v1.x + v1.y*v1.y + v1.z*v1.z + v1.w*v1.w
                 + v2.x*v2.x + v2.y*v2.y + v2.z*v2.z + v2.w*v2.w
                 + v3.x*v3.x + v3.y*v3.y + v3.z*v3.z + v3.w*v3.w;
        #pragma unroll
        for (int off = 32; off; off >>= 1) {
            ss += __shfl_xor(ss, off, 64);
        }
        const float s = 1.0f / fmaxf(sqrtf(ss), EPS);

        __builtin_nontemporal_store(v0 * s, &dst[lane]);
        __builtin_nontemporal_store(v1 * s, &dst[lane + 64]);
        __builtin_nontemporal_store(v2 * s, &dst[lane + 128]);
        __builtin_nontemporal_store(v3 * s, &dst[lane + 192]);
    }
}

// ---------------------------------------------------------------------------
extern "C" void kernel_launch(void* const* d_in, const int* in_sizes, int n_in,
                              void* d_out, int out_size, void* d_ws, size_t ws_size,
                              hipStream_t stream)
{
    const float* embeddings = (const float*)d_in[0];   // (4096, 1024) f32
    const int*   labels     = (const int*)d_in[1];     // (4096,) int
    const float* queue      = (const float*)d_in[2];   // (100, 256, 1024) f32
    const int*   queue_ptr  = (const int*)d_in[3];     // (100,) int

    float* out = (float*)d_out;                        // (100, 256, 1024) f32
    int*   inv = (int*)d_ws;                           // 25600 ints scratch

    // 0) inv = -1
    (void)hipMemsetAsync(inv, 0xFF, TOTAL_ROWS * sizeof(int), stream);

    // 1) FIFO slots + inverse map (16 blocks x 256 threads)
    compute_slots_kernel<<<BATCH / 256, 256, 0, stream>>>(labels, queue_ptr, inv);

    // 2) fused copy/normalize-scatter: one wave per row, 4 rows per block
    fused_write_kernel<<<TOTAL_ROWS / 4, 256, 0, stream>>>(
        queue, embeddings, inv, out);
}